// Round 1
// baseline (7021.290 us; speedup 1.0000x reference)
//
#include <hip/hip_runtime.h>
#include <math.h>

#define EMB 1024
#define HEADS 16
#define HEAD_DIM 64
#define FF_DIM 4096
#define SEQ 2048
#define BATCH 2
#define NTOK (BATCH * SEQ)   // 4096 rows
#define LN_EPS 1e-5f

// ---------------- LayerNorm: one block per row (1024 cols, 256 thr x float4) ----------
__global__ __launch_bounds__(256) void ln_kernel(const float* __restrict__ x,
                                                 const float* __restrict__ scale,
                                                 const float* __restrict__ shift,
                                                 float* __restrict__ out) {
    int row = blockIdx.x;
    int tid = threadIdx.x;
    const float4 xv = ((const float4*)(x + (size_t)row * EMB))[tid];
    float s  = xv.x + xv.y + xv.z + xv.w;
    float ss = xv.x * xv.x + xv.y * xv.y + xv.z * xv.z + xv.w * xv.w;
    __shared__ float2 red[256];
    red[tid] = make_float2(s, ss);
    __syncthreads();
    for (int off = 128; off > 0; off >>= 1) {
        if (tid < off) {
            red[tid].x += red[tid + off].x;
            red[tid].y += red[tid + off].y;
        }
        __syncthreads();
    }
    float mean = red[0].x * (1.0f / EMB);
    float var  = red[0].y * (1.0f / EMB) - mean * mean;
    float rstd = rsqrtf(var + LN_EPS);
    float4 sc4 = ((const float4*)scale)[tid];
    float4 sh4 = ((const float4*)shift)[tid];
    float4 o;
    o.x = sc4.x * (xv.x - mean) * rstd + sh4.x;
    o.y = sc4.y * (xv.y - mean) * rstd + sh4.y;
    o.z = sc4.z * (xv.z - mean) * rstd + sh4.z;
    o.w = sc4.w * (xv.w - mean) * rstd + sh4.w;
    ((float4*)(out + (size_t)row * EMB))[tid] = o;
}

// ---------------- GELU (tanh approx, matches reference) ------------------------------
__device__ __forceinline__ float gelu_f(float x) {
    const float c = 0.7978845608028654f;  // sqrt(2/pi)
    float x3 = x * x * x;
    return 0.5f * x * (1.0f + tanhf(c * (x + 0.044715f * x3)));
}

// ---------------- fp32 GEMM: C[M,N] = A[M,K] @ B[K,N] (+bias)(+gelu)(+residual) -------
// 64x64 tile, 256 threads, 4x4 micro-tile per thread, TK=16.
__global__ __launch_bounds__(256) void gemm_kernel(const float* __restrict__ A,
                                                   const float* __restrict__ B,
                                                   float* __restrict__ C,
                                                   int M, int N, int K,
                                                   const float* __restrict__ bias,
                                                   const float* __restrict__ residual,
                                                   int do_gelu) {
    __shared__ float As[16][68];  // As[k][m], padded row stride 68 (16B-aligned rows)
    __shared__ float Bs[16][68];  // Bs[k][n]
    int tid = threadIdx.x;
    int bc = blockIdx.x, br = blockIdx.y;
    int tx = tid & 15, ty = tid >> 4;

    float acc[4][4] = {};

    int am = tid >> 2;             // 0..63 : A row within tile
    int ak = (tid & 3) * 4;        // 0,4,8,12 : k offset
    int bk = tid >> 4;             // 0..15 : B k-row within tile
    int bn = (tid & 15) * 4;       // col offset

    const float* Aptr = A + (size_t)(br * 64 + am) * K + ak;
    const float* Bptr = B + (size_t)bk * N + (size_t)bc * 64 + bn;

    for (int kt = 0; kt < K; kt += 16) {
        float4 a4 = *(const float4*)(Aptr + kt);
        float4 b4 = *(const float4*)(Bptr + (size_t)kt * N);
        As[ak + 0][am] = a4.x;
        As[ak + 1][am] = a4.y;
        As[ak + 2][am] = a4.z;
        As[ak + 3][am] = a4.w;
        *(float4*)&Bs[bk][bn] = b4;
        __syncthreads();
#pragma unroll
        for (int k = 0; k < 16; ++k) {
            float4 a = *(const float4*)&As[k][ty * 4];
            float4 b = *(const float4*)&Bs[k][tx * 4];
            float av[4] = {a.x, a.y, a.z, a.w};
            float bv[4] = {b.x, b.y, b.z, b.w};
#pragma unroll
            for (int i = 0; i < 4; ++i)
#pragma unroll
                for (int j = 0; j < 4; ++j)
                    acc[i][j] = fmaf(av[i], bv[j], acc[i][j]);
        }
        __syncthreads();
    }

    int m0 = br * 64 + ty * 4;
    int n0 = bc * 64 + tx * 4;
    float4 bias4 = bias ? *(const float4*)&bias[n0] : make_float4(0.f, 0.f, 0.f, 0.f);
#pragma unroll
    for (int i = 0; i < 4; ++i) {
        size_t off = (size_t)(m0 + i) * N + n0;
        float v[4];
#pragma unroll
        for (int j = 0; j < 4; ++j) v[j] = acc[i][j];
        v[0] += bias4.x; v[1] += bias4.y; v[2] += bias4.z; v[3] += bias4.w;
        if (do_gelu) {
#pragma unroll
            for (int j = 0; j < 4; ++j) v[j] = gelu_f(v[j]);
        }
        if (residual) {
            float4 r = *(const float4*)&residual[off];
            v[0] += r.x; v[1] += r.y; v[2] += r.z; v[3] += r.w;
        }
        float4 o = make_float4(v[0], v[1], v[2], v[3]);
        *(float4*)&C[off] = o;
    }
}

// ---------------- causal attention: one block per (b, head, query row) ----------------
// q,k,v,ctx are [NTOK, EMB] with head h at columns [h*64, h*64+64).
__global__ __launch_bounds__(256) void attn_kernel(const float* __restrict__ q,
                                                   const float* __restrict__ k,
                                                   const float* __restrict__ v,
                                                   float* __restrict__ ctx) {
    int qi = blockIdx.x;           // 0..2047
    int h  = blockIdx.y;           // 0..15
    int b  = blockIdx.z;           // 0..1
    int tid = threadIdx.x;

    __shared__ float sc[SEQ];      // scores / probs
    __shared__ float red[256];
    __shared__ float qrow[HEAD_DIM];

    size_t base = ((size_t)b * SEQ) * EMB + (size_t)h * HEAD_DIM;

    if (tid < HEAD_DIM) qrow[tid] = q[base + (size_t)qi * EMB + tid];
    __syncthreads();

    // pass 1: scores for j <= qi
    for (int j = tid; j <= qi; j += 256) {
        const float* kr = k + base + (size_t)j * EMB;
        float dot = 0.f;
#pragma unroll
        for (int d = 0; d < HEAD_DIM; d += 4) {
            float4 kv = *(const float4*)(kr + d);
            float4 qv = *(const float4*)(qrow + d);
            dot = fmaf(kv.x, qv.x, dot);
            dot = fmaf(kv.y, qv.y, dot);
            dot = fmaf(kv.z, qv.z, dot);
            dot = fmaf(kv.w, qv.w, dot);
        }
        sc[j] = dot * 0.125f;      // 1/sqrt(64)
    }
    __syncthreads();

    // row max
    float lm = -1e30f;
    for (int j = tid; j <= qi; j += 256) lm = fmaxf(lm, sc[j]);
    red[tid] = lm;
    __syncthreads();
    for (int off = 128; off > 0; off >>= 1) {
        if (tid < off) red[tid] = fmaxf(red[tid], red[tid + off]);
        __syncthreads();
    }
    float m = red[0];
    __syncthreads();

    // exp + sum
    float ls = 0.f;
    for (int j = tid; j <= qi; j += 256) {
        float e = __expf(sc[j] - m);
        sc[j] = e;
        ls += e;
    }
    red[tid] = ls;
    __syncthreads();
    for (int off = 128; off > 0; off >>= 1) {
        if (tid < off) red[tid] += red[tid + off];
        __syncthreads();
    }
    float inv_l = 1.0f / red[0];
    __syncthreads();

    // pass 3: ctx[d] = inv_l * sum_j p_j * v[j][d]
    int d  = tid & 63;
    int c4 = tid >> 6;
    float partial = 0.f;
    for (int j = c4; j <= qi; j += 4)
        partial = fmaf(sc[j], v[base + (size_t)j * EMB + d], partial);
    red[tid] = partial;
    __syncthreads();
    if (tid < HEAD_DIM) {
        float cv = (red[tid] + red[tid + 64] + red[tid + 128] + red[tid + 192]) * inv_l;
        ctx[base + (size_t)qi * EMB + tid] = cv;
    }
}

extern "C" void kernel_launch(void* const* d_in, const int* in_sizes, int n_in,
                              void* d_out, int out_size, void* d_ws, size_t ws_size,
                              hipStream_t stream) {
    const float* x    = (const float*)d_in[0];
    const float* Wq   = (const float*)d_in[1];
    const float* Wk   = (const float*)d_in[2];
    const float* Wv   = (const float*)d_in[3];
    const float* Wo   = (const float*)d_in[4];
    const float* bo   = (const float*)d_in[5];
    const float* W1   = (const float*)d_in[6];
    const float* b1   = (const float*)d_in[7];
    const float* W2   = (const float*)d_in[8];
    const float* b2   = (const float*)d_in[9];
    const float* ln1s = (const float*)d_in[10];
    const float* ln1b = (const float*)d_in[11];
    const float* ln2s = (const float*)d_in[12];
    const float* ln2b = (const float*)d_in[13];
    float* out = (float*)d_out;

    // workspace layout (floats). 96 MiB total.
    const size_t TOK_EMB = (size_t)NTOK * EMB;            // 4M floats
    float* ws  = (float*)d_ws;
    float* h   = ws;                                      // [0, 4M)
    float* q   = ws + 1 * TOK_EMB;                        // [4M, 8M)
    float* k   = ws + 2 * TOK_EMB;                        // [8M, 12M)
    float* v   = ws + 3 * TOK_EMB;                        // [12M, 16M)
    float* ctx = ws + 4 * TOK_EMB;                        // [16M, 20M)
    float* x1  = ws + 5 * TOK_EMB;                        // [20M, 24M)
    float* h2  = ws;                                      // reuse h (dead after QKV)
    float* u   = ws + 1 * TOK_EMB;                        // reuse q..ctx (16M floats)

    // 1) LN1
    ln_kernel<<<NTOK, 256, 0, stream>>>(x, ln1s, ln1b, h);

    // 2) QKV projections: [4096,1024] @ [1024,1024]
    dim3 gProj(EMB / 64, NTOK / 64);  // (16, 64)
    gemm_kernel<<<gProj, 256, 0, stream>>>(h, Wq, q, NTOK, EMB, EMB, nullptr, nullptr, 0);
    gemm_kernel<<<gProj, 256, 0, stream>>>(h, Wk, k, NTOK, EMB, EMB, nullptr, nullptr, 0);
    gemm_kernel<<<gProj, 256, 0, stream>>>(h, Wv, v, NTOK, EMB, EMB, nullptr, nullptr, 0);

    // 3) causal attention
    dim3 gAttn(SEQ, HEADS, BATCH);
    attn_kernel<<<gAttn, 256, 0, stream>>>(q, k, v, ctx);

    // 4) out proj + bias + residual: x1 = x + ctx@Wo + bo
    gemm_kernel<<<gProj, 256, 0, stream>>>(ctx, Wo, x1, NTOK, EMB, EMB, bo, x, 0);

    // 5) LN2
    ln_kernel<<<NTOK, 256, 0, stream>>>(x1, ln2s, ln2b, h2);

    // 6) FFN up + GELU: u = gelu(h2@W1 + b1)   [4096,1024]@[1024,4096]
    dim3 gUp(FF_DIM / 64, NTOK / 64);  // (64, 64)
    gemm_kernel<<<gUp, 256, 0, stream>>>(h2, W1, u, NTOK, FF_DIM, EMB, b1, nullptr, 1);

    // 7) FFN down + bias + residual: out = x1 + u@W2 + b2   [4096,4096]@[4096,1024]
    dim3 gDown(EMB / 64, NTOK / 64);  // (16, 64)
    gemm_kernel<<<gDown, 256, 0, stream>>>(u, W2, out, NTOK, EMB, FF_DIM, b2, x1, 0);
}

// Round 2
// 2022.982 us; speedup vs baseline: 3.4708x; 3.4708x over previous
//
#include <hip/hip_runtime.h>
#include <math.h>

#define EMB 1024
#define HEADS 16
#define HEAD_DIM 64
#define FF_DIM 4096
#define SEQ 2048
#define BATCH 2
#define NTOK (BATCH * SEQ)   // 4096 rows
#define LN_EPS 1e-5f

// ---------------- LayerNorm: one block per row (1024 cols, 256 thr x float4) ----------
__global__ __launch_bounds__(256) void ln_kernel(const float* __restrict__ x,
                                                 const float* __restrict__ scale,
                                                 const float* __restrict__ shift,
                                                 float* __restrict__ out) {
    int row = blockIdx.x;
    int tid = threadIdx.x;
    const float4 xv = ((const float4*)(x + (size_t)row * EMB))[tid];
    float s  = xv.x + xv.y + xv.z + xv.w;
    float ss = xv.x * xv.x + xv.y * xv.y + xv.z * xv.z + xv.w * xv.w;
    __shared__ float2 red[256];
    red[tid] = make_float2(s, ss);
    __syncthreads();
    for (int off = 128; off > 0; off >>= 1) {
        if (tid < off) {
            red[tid].x += red[tid + off].x;
            red[tid].y += red[tid + off].y;
        }
        __syncthreads();
    }
    float mean = red[0].x * (1.0f / EMB);
    float var  = red[0].y * (1.0f / EMB) - mean * mean;
    float rstd = rsqrtf(var + LN_EPS);
    float4 sc4 = ((const float4*)scale)[tid];
    float4 sh4 = ((const float4*)shift)[tid];
    float4 o;
    o.x = sc4.x * (xv.x - mean) * rstd + sh4.x;
    o.y = sc4.y * (xv.y - mean) * rstd + sh4.y;
    o.z = sc4.z * (xv.z - mean) * rstd + sh4.z;
    o.w = sc4.w * (xv.w - mean) * rstd + sh4.w;
    ((float4*)(out + (size_t)row * EMB))[tid] = o;
}

// ---------------- GELU (tanh approx, matches reference) ------------------------------
__device__ __forceinline__ float gelu_f(float x) {
    const float c = 0.7978845608028654f;  // sqrt(2/pi)
    float x3 = x * x * x;
    return 0.5f * x * (1.0f + tanhf(c * (x + 0.044715f * x3)));
}

// ---------------- fp32 GEMM: C[M,N] = A[M,K] @ B[K,N] (+bias)(+gelu)(+residual) -------
// 64x64 tile, 256 threads, 4x4 micro-tile per thread, TK=16.
__global__ __launch_bounds__(256) void gemm_kernel(const float* __restrict__ A,
                                                   const float* __restrict__ B,
                                                   float* __restrict__ C,
                                                   int M, int N, int K,
                                                   const float* __restrict__ bias,
                                                   const float* __restrict__ residual,
                                                   int do_gelu) {
    __shared__ float As[16][68];  // As[k][m]
    __shared__ float Bs[16][68];  // Bs[k][n]
    int tid = threadIdx.x;
    int bc = blockIdx.x, br = blockIdx.y;
    int tx = tid & 15, ty = tid >> 4;

    float acc[4][4] = {};

    int am = tid >> 2;             // 0..63 : A row within tile
    int ak = (tid & 3) * 4;        // 0,4,8,12 : k offset
    int bk = tid >> 4;             // 0..15 : B k-row within tile
    int bn = (tid & 15) * 4;       // col offset

    const float* Aptr = A + (size_t)(br * 64 + am) * K + ak;
    const float* Bptr = B + (size_t)bk * N + (size_t)bc * 64 + bn;

    for (int kt = 0; kt < K; kt += 16) {
        float4 a4 = *(const float4*)(Aptr + kt);
        float4 b4 = *(const float4*)(Bptr + (size_t)kt * N);
        As[ak + 0][am] = a4.x;
        As[ak + 1][am] = a4.y;
        As[ak + 2][am] = a4.z;
        As[ak + 3][am] = a4.w;
        *(float4*)&Bs[bk][bn] = b4;
        __syncthreads();
#pragma unroll
        for (int k = 0; k < 16; ++k) {
            float4 a = *(const float4*)&As[k][ty * 4];
            float4 b = *(const float4*)&Bs[k][tx * 4];
            float av[4] = {a.x, a.y, a.z, a.w};
            float bv[4] = {b.x, b.y, b.z, b.w};
#pragma unroll
            for (int i = 0; i < 4; ++i)
#pragma unroll
                for (int j = 0; j < 4; ++j)
                    acc[i][j] = fmaf(av[i], bv[j], acc[i][j]);
        }
        __syncthreads();
    }

    int m0 = br * 64 + ty * 4;
    int n0 = bc * 64 + tx * 4;
    float4 bias4 = bias ? *(const float4*)&bias[n0] : make_float4(0.f, 0.f, 0.f, 0.f);
#pragma unroll
    for (int i = 0; i < 4; ++i) {
        size_t off = (size_t)(m0 + i) * N + n0;
        float v[4];
#pragma unroll
        for (int j = 0; j < 4; ++j) v[j] = acc[i][j];
        v[0] += bias4.x; v[1] += bias4.y; v[2] += bias4.z; v[3] += bias4.w;
        if (do_gelu) {
#pragma unroll
            for (int j = 0; j < 4; ++j) v[j] = gelu_f(v[j]);
        }
        if (residual) {
            float4 r = *(const float4*)&residual[off];
            v[0] += r.x; v[1] += r.y; v[2] += r.z; v[3] += r.w;
        }
        float4 o = make_float4(v[0], v[1], v[2], v[3]);
        *(float4*)&C[off] = o;
    }
}

// ---------------- flash-style tiled causal attention ---------------------------------
// One block per (b, head, 64-query tile). Iterate 64-key tiles (kt <= qt).
// 256 threads as 16x16 micro-tile grid; each thread owns a 4x4 S/P tile and a
// 4(query)x4(dim) O accumulator. Online softmax with wave-local shuffles over
// the 16-lane row group (lanes ty*16+tx, same ty => same 16-lane group).
__global__ __launch_bounds__(256) void flash_attn_kernel(const float* __restrict__ q,
                                                         const float* __restrict__ k,
                                                         const float* __restrict__ v,
                                                         float* __restrict__ ctx) {
    int qt = blockIdx.x;           // 0..31
    int h  = blockIdx.y;           // 0..15
    int b  = blockIdx.z;           // 0..1
    int tid = threadIdx.x;
    int tx = tid & 15, ty = tid >> 4;

    __shared__ float Qs[64][68];   // [d][qrow]  (transposed)
    __shared__ float Ks[64][68];   // [d][krow]  (transposed)
    __shared__ float Vs[64][68];   // [krow][d]  (row-major)
    __shared__ float Ps[64][68];   // [qrow][krow]

    size_t base = ((size_t)b * SEQ) * EMB + (size_t)h * HEAD_DIM;

    // load Q tile (64 rows x 64 dims), store transposed
#pragma unroll
    for (int t = 0; t < 4; ++t) {
        int f = tid + t * 256;
        int row = f >> 4, c4 = (f & 15) * 4;
        float4 qv = *(const float4*)(q + base + (size_t)(qt * 64 + row) * EMB + c4);
        Qs[c4 + 0][row] = qv.x;
        Qs[c4 + 1][row] = qv.y;
        Qs[c4 + 2][row] = qv.z;
        Qs[c4 + 3][row] = qv.w;
    }

    float m_i[4], l_i[4], o[4][4];
#pragma unroll
    for (int i = 0; i < 4; ++i) {
        m_i[i] = -1e30f;
        l_i[i] = 0.f;
#pragma unroll
        for (int j = 0; j < 4; ++j) o[i][j] = 0.f;
    }

    for (int kt = 0; kt <= qt; ++kt) {
        __syncthreads();   // previous PV done reading Vs/Ps before restage
#pragma unroll
        for (int t = 0; t < 4; ++t) {
            int f = tid + t * 256;
            int row = f >> 4, c4 = (f & 15) * 4;
            const float* kp = k + base + (size_t)(kt * 64 + row) * EMB + c4;
            float4 kv = *(const float4*)kp;
            Ks[c4 + 0][row] = kv.x;
            Ks[c4 + 1][row] = kv.y;
            Ks[c4 + 2][row] = kv.z;
            Ks[c4 + 3][row] = kv.w;
            const float* vp = v + base + (size_t)(kt * 64 + row) * EMB + c4;
            *(float4*)&Vs[row][c4] = *(const float4*)vp;
        }
        __syncthreads();

        // S = Q K^T  (4x4 per thread)
        float s[4][4] = {};
#pragma unroll 16
        for (int d = 0; d < 64; ++d) {
            float4 a = *(const float4*)&Qs[d][ty * 4];
            float4 bb = *(const float4*)&Ks[d][tx * 4];
            float av[4] = {a.x, a.y, a.z, a.w};
            float bv[4] = {bb.x, bb.y, bb.z, bb.w};
#pragma unroll
            for (int i = 0; i < 4; ++i)
#pragma unroll
                for (int j = 0; j < 4; ++j)
                    s[i][j] = fmaf(av[i], bv[j], s[i][j]);
        }

        bool diag = (kt == qt);
#pragma unroll
        for (int i = 0; i < 4; ++i) {
            int ri = ty * 4 + i;
#pragma unroll
            for (int j = 0; j < 4; ++j) {
                float sv = s[i][j] * 0.125f;   // 1/sqrt(64)
                if (diag && (tx * 4 + j) > ri) sv = -1e30f;
                s[i][j] = sv;
            }
            float rm = fmaxf(fmaxf(s[i][0], s[i][1]), fmaxf(s[i][2], s[i][3]));
#pragma unroll
            for (int msk = 1; msk < 16; msk <<= 1)
                rm = fmaxf(rm, __shfl_xor(rm, msk));
            float m_new = fmaxf(m_i[i], rm);
            float p0 = __expf(s[i][0] - m_new);
            float p1 = __expf(s[i][1] - m_new);
            float p2 = __expf(s[i][2] - m_new);
            float p3 = __expf(s[i][3] - m_new);
            float rs = p0 + p1 + p2 + p3;
#pragma unroll
            for (int msk = 1; msk < 16; msk <<= 1)
                rs += __shfl_xor(rs, msk);
            float alpha = __expf(m_i[i] - m_new);
            l_i[i] = l_i[i] * alpha + rs;
            m_i[i] = m_new;
#pragma unroll
            for (int j = 0; j < 4; ++j) o[i][j] *= alpha;
            *(float4*)&Ps[ri][tx * 4] = make_float4(p0, p1, p2, p3);
        }
        __syncthreads();   // Ps visible before PV

        // O += P V   (thread: rows ty*4..+3, dims tx*4..+3)
#pragma unroll
        for (int c0 = 0; c0 < 16; ++c0) {
            float4 v0 = *(const float4*)&Vs[c0 * 4 + 0][tx * 4];
            float4 v1 = *(const float4*)&Vs[c0 * 4 + 1][tx * 4];
            float4 v2 = *(const float4*)&Vs[c0 * 4 + 2][tx * 4];
            float4 v3 = *(const float4*)&Vs[c0 * 4 + 3][tx * 4];
#pragma unroll
            for (int i = 0; i < 4; ++i) {
                float4 pr = *(const float4*)&Ps[ty * 4 + i][c0 * 4];
                o[i][0] = fmaf(pr.x, v0.x, o[i][0]);
                o[i][1] = fmaf(pr.x, v0.y, o[i][1]);
                o[i][2] = fmaf(pr.x, v0.z, o[i][2]);
                o[i][3] = fmaf(pr.x, v0.w, o[i][3]);
                o[i][0] = fmaf(pr.y, v1.x, o[i][0]);
                o[i][1] = fmaf(pr.y, v1.y, o[i][1]);
                o[i][2] = fmaf(pr.y, v1.z, o[i][2]);
                o[i][3] = fmaf(pr.y, v1.w, o[i][3]);
                o[i][0] = fmaf(pr.z, v2.x, o[i][0]);
                o[i][1] = fmaf(pr.z, v2.y, o[i][1]);
                o[i][2] = fmaf(pr.z, v2.z, o[i][2]);
                o[i][3] = fmaf(pr.z, v2.w, o[i][3]);
                o[i][0] = fmaf(pr.w, v3.x, o[i][0]);
                o[i][1] = fmaf(pr.w, v3.y, o[i][1]);
                o[i][2] = fmaf(pr.w, v3.z, o[i][2]);
                o[i][3] = fmaf(pr.w, v3.w, o[i][3]);
            }
        }
    }

    // normalize + write
#pragma unroll
    for (int i = 0; i < 4; ++i) {
        float inv = 1.0f / l_i[i];
        float4 ov = make_float4(o[i][0] * inv, o[i][1] * inv, o[i][2] * inv, o[i][3] * inv);
        *(float4*)(ctx + base + (size_t)(qt * 64 + ty * 4 + i) * EMB + tx * 4) = ov;
    }
}

extern "C" void kernel_launch(void* const* d_in, const int* in_sizes, int n_in,
                              void* d_out, int out_size, void* d_ws, size_t ws_size,
                              hipStream_t stream) {
    const float* x    = (const float*)d_in[0];
    const float* Wq   = (const float*)d_in[1];
    const float* Wk   = (const float*)d_in[2];
    const float* Wv   = (const float*)d_in[3];
    const float* Wo   = (const float*)d_in[4];
    const float* bo   = (const float*)d_in[5];
    const float* W1   = (const float*)d_in[6];
    const float* b1   = (const float*)d_in[7];
    const float* W2   = (const float*)d_in[8];
    const float* b2   = (const float*)d_in[9];
    const float* ln1s = (const float*)d_in[10];
    const float* ln1b = (const float*)d_in[11];
    const float* ln2s = (const float*)d_in[12];
    const float* ln2b = (const float*)d_in[13];
    float* out = (float*)d_out;

    const size_t TOK_EMB = (size_t)NTOK * EMB;            // 4M floats
    float* ws  = (float*)d_ws;
    float* h   = ws;                                      // [0, 4M)
    float* q   = ws + 1 * TOK_EMB;
    float* k   = ws + 2 * TOK_EMB;
    float* v   = ws + 3 * TOK_EMB;
    float* ctx = ws + 4 * TOK_EMB;
    float* x1  = ws + 5 * TOK_EMB;
    float* h2  = ws;                                      // reuse h
    float* u   = ws + 1 * TOK_EMB;                        // reuse q..ctx

    // 1) LN1
    ln_kernel<<<NTOK, 256, 0, stream>>>(x, ln1s, ln1b, h);

    // 2) QKV projections
    dim3 gProj(EMB / 64, NTOK / 64);
    gemm_kernel<<<gProj, 256, 0, stream>>>(h, Wq, q, NTOK, EMB, EMB, nullptr, nullptr, 0);
    gemm_kernel<<<gProj, 256, 0, stream>>>(h, Wk, k, NTOK, EMB, EMB, nullptr, nullptr, 0);
    gemm_kernel<<<gProj, 256, 0, stream>>>(h, Wv, v, NTOK, EMB, EMB, nullptr, nullptr, 0);

    // 3) tiled causal attention
    dim3 gAttn(SEQ / 64, HEADS, BATCH);
    flash_attn_kernel<<<gAttn, 256, 0, stream>>>(q, k, v, ctx);

    // 4) out proj + bias + residual
    gemm_kernel<<<gProj, 256, 0, stream>>>(ctx, Wo, x1, NTOK, EMB, EMB, bo, x, 0);

    // 5) LN2
    ln_kernel<<<NTOK, 256, 0, stream>>>(x1, ln2s, ln2b, h2);

    // 6) FFN up + GELU
    dim3 gUp(FF_DIM / 64, NTOK / 64);
    gemm_kernel<<<gUp, 256, 0, stream>>>(h2, W1, u, NTOK, FF_DIM, EMB, b1, nullptr, 1);

    // 7) FFN down + bias + residual
    dim3 gDown(EMB / 64, NTOK / 64);
    gemm_kernel<<<gDown, 256, 0, stream>>>(u, W2, out, NTOK, EMB, FF_DIM, b2, x1, 0);
}

// Round 3
// 1287.970 us; speedup vs baseline: 5.4514x; 1.5707x over previous
//
#include <hip/hip_runtime.h>
#include <hip/hip_bf16.h>
#include <math.h>

#define EMB 1024
#define HEADS 16
#define HEAD_DIM 64
#define FF_DIM 4096
#define SEQ 2048
#define BATCH 2
#define NTOK (BATCH * SEQ)   // 4096 rows
#define LN_EPS 1e-5f
#define QKV_N 3072

typedef __attribute__((ext_vector_type(8))) short s8v;   // 8 bf16 (4 VGPRs)
typedef __attribute__((ext_vector_type(4))) float f4v;   // MFMA accumulator

__device__ __forceinline__ unsigned short f2bf(float f) {
    union { __hip_bfloat16 h; unsigned short u; } cv;
    cv.h = __float2bfloat16(f);
    return cv.u;
}

__device__ __forceinline__ float gelu_f(float x) {
    const float c = 0.7978845608028654f;  // sqrt(2/pi)
    float x3 = x * x * x;
    return 0.5f * x * (1.0f + tanhf(c * (x + 0.044715f * x3)));
}

#define GLDS(gp, lp)                                                        \
    __builtin_amdgcn_global_load_lds(                                       \
        (const __attribute__((address_space(1))) void*)(gp),                \
        (__attribute__((address_space(3))) void*)(lp), 16, 0, 0)

// ---------------- LayerNorm -> bf16 out ----------------------------------------------
__global__ __launch_bounds__(256) void ln_bf16_kernel(const float* __restrict__ x,
                                                      const float* __restrict__ scale,
                                                      const float* __restrict__ shift,
                                                      unsigned short* __restrict__ out) {
    int row = blockIdx.x;
    int tid = threadIdx.x;
    const float4 xv = ((const float4*)(x + (size_t)row * EMB))[tid];
    float s  = xv.x + xv.y + xv.z + xv.w;
    float ss = xv.x * xv.x + xv.y * xv.y + xv.z * xv.z + xv.w * xv.w;
    __shared__ float2 red[256];
    red[tid] = make_float2(s, ss);
    __syncthreads();
    for (int off = 128; off > 0; off >>= 1) {
        if (tid < off) {
            red[tid].x += red[tid + off].x;
            red[tid].y += red[tid + off].y;
        }
        __syncthreads();
    }
    float mean = red[0].x * (1.0f / EMB);
    float var  = red[0].y * (1.0f / EMB) - mean * mean;
    float rstd = rsqrtf(var + LN_EPS);
    float4 sc4 = ((const float4*)scale)[tid];
    float4 sh4 = ((const float4*)shift)[tid];
    ushort4 o;
    o.x = f2bf(sc4.x * (xv.x - mean) * rstd + sh4.x);
    o.y = f2bf(sc4.y * (xv.y - mean) * rstd + sh4.y);
    o.z = f2bf(sc4.z * (xv.z - mean) * rstd + sh4.z);
    o.w = f2bf(sc4.w * (xv.w - mean) * rstd + sh4.w);
    *(ushort4*)(out + (size_t)row * EMB + tid * 4) = o;
}

// ---------------- fp32 [K][N] -> bf16 [N][K] transpose-convert ------------------------
__global__ __launch_bounds__(256) void tconv_kernel(const float* __restrict__ W,
                                                    unsigned short* __restrict__ Wt,
                                                    int K, int N) {
    __shared__ float t[64][65];
    int n0 = blockIdx.x * 64, k0 = blockIdx.y * 64;
    int tid = threadIdx.x;
#pragma unroll
    for (int it = 0; it < 4; ++it) {
        int f = tid + it * 256;
        int r = f >> 4, c = (f & 15) * 4;
        float4 w = *(const float4*)(W + (size_t)(k0 + r) * N + n0 + c);
        t[r][c] = w.x; t[r][c + 1] = w.y; t[r][c + 2] = w.z; t[r][c + 3] = w.w;
    }
    __syncthreads();
#pragma unroll
    for (int it = 0; it < 4; ++it) {
        int f = tid + it * 256;
        int rn = f >> 4, ck = (f & 15) * 4;
        ushort4 o;
        o.x = f2bf(t[ck + 0][rn]);
        o.y = f2bf(t[ck + 1][rn]);
        o.z = f2bf(t[ck + 2][rn]);
        o.w = f2bf(t[ck + 3][rn]);
        *(ushort4*)(Wt + (size_t)(n0 + rn) * K + k0 + ck) = o;
    }
}

// ---------------- bf16 MFMA GEMM: C[M,N] = A[M,K] @ Bt[N,K]^T (+bias)(+gelu)(+res) ----
// 128x128 tile, BK=32, 256 threads = 4 waves in 2x2, each wave 4x4 of 16x16x32 MFMA.
// LDS: k-chunk-major planes [4][128 rows][8 bf16] -> conflict-free ds_read_b128,
// and linear chunk order satisfies global_load_lds's base+lane*16 constraint.
__global__ __launch_bounds__(256) void gemm_bf16_kernel(
    const unsigned short* __restrict__ A,   // [M,K] bf16
    const unsigned short* __restrict__ Bt,  // [N,K] bf16
    float* __restrict__ Cf,                 // fp32 out (or null)
    unsigned short* __restrict__ Cb,        // bf16 out (or null)
    int M, int N, int K,
    const float* __restrict__ bias,
    const float* __restrict__ residual,
    int do_gelu)
{
    __shared__ short As[4096];   // 4 planes x 128 rows x 8 bf16 = 8 KiB
    __shared__ short Bs[4096];

    int tid = threadIdx.x;
    int m0 = blockIdx.y * 128;
    int n0 = blockIdx.x * 128;
    int wv = tid >> 6, lane = tid & 63;
    int wr = wv >> 1, wc = wv & 1;

    f4v acc[4][4];
#pragma unroll
    for (int i = 0; i < 4; ++i)
#pragma unroll
        for (int j = 0; j < 4; ++j) {
            f4v z = {0.f, 0.f, 0.f, 0.f};
            acc[i][j] = z;
        }

    // staging: chunk c -> (kc = c>>7, row = c&127); lds byte = c*16 (linear in c)
    int ra = tid & 127, ka = tid >> 7;   // issue0: chunk=tid; issue1: chunk=tid+256 (kc+2)
    const char* Ag0 = (const char*)A + (size_t)(m0 + ra) * (K << 1) + ka * 16;
    const char* Bg0 = (const char*)Bt + (size_t)(n0 + ra) * (K << 1) + ka * 16;
    short* Al0 = As + tid * 8;
    short* Al1 = As + (tid + 256) * 8;
    short* Bl0 = Bs + tid * 8;
    short* Bl1 = Bs + (tid + 256) * 8;

    int kgrp = lane >> 4;
    const short* Af = As + ((size_t)kgrp * 128 + wr * 64 + (lane & 15)) * 8;
    const short* Bf = Bs + ((size_t)kgrp * 128 + wc * 64 + (lane & 15)) * 8;

    int Kb = K << 1;   // bytes per row
    for (int kb = 0; kb < Kb; kb += 64) {
        __syncthreads();   // previous iter's ds_reads done before overwrite
        GLDS(Ag0 + kb, Al0);
        GLDS(Ag0 + kb + 32, Al1);
        GLDS(Bg0 + kb, Bl0);
        GLDS(Bg0 + kb + 32, Bl1);
        __syncthreads();   // drains vmcnt (compiler emits waitcnt before barrier)

        s8v af[4], bf[4];
#pragma unroll
        for (int i = 0; i < 4; ++i) af[i] = *(const s8v*)(Af + i * 128);
#pragma unroll
        for (int j = 0; j < 4; ++j) bf[j] = *(const s8v*)(Bf + j * 128);
#pragma unroll
        for (int i = 0; i < 4; ++i)
#pragma unroll
            for (int j = 0; j < 4; ++j)
                acc[i][j] = __builtin_amdgcn_mfma_f32_16x16x32_bf16(af[i], bf[j], acc[i][j], 0, 0, 0);
    }

    // epilogue: C/D layout col=lane&15, row=(lane>>4)*4+reg
    int cn  = n0 + wc * 64 + (lane & 15);
    int cm0 = m0 + wr * 64 + (lane >> 4) * 4;
#pragma unroll
    for (int j = 0; j < 4; ++j) {
        int gn = cn + j * 16;
        float bj = bias ? bias[gn] : 0.f;
#pragma unroll
        for (int i = 0; i < 4; ++i) {
#pragma unroll
            for (int r = 0; r < 4; ++r) {
                int gm = cm0 + i * 16 + r;
                float vv = acc[i][j][r] + bj;
                if (do_gelu) vv = gelu_f(vv);
                if (residual) vv += residual[(size_t)gm * N + gn];
                if (Cf) Cf[(size_t)gm * N + gn] = vv;
                else    Cb[(size_t)gm * N + gn] = f2bf(vv);
            }
        }
    }
}

// ---------------- flash-style tiled causal attention (fp32, qkv fused input) ----------
// q,k,v at column offsets 0/1024/2048 of qkv [NTOK, 3072]; ctx out bf16 [NTOK, EMB].
__global__ __launch_bounds__(256) void flash_attn_kernel(const float* __restrict__ qkv,
                                                         unsigned short* __restrict__ ctx) {
    int qt = blockIdx.x;           // 0..31
    int h  = blockIdx.y;           // 0..15
    int b  = blockIdx.z;           // 0..1
    int tid = threadIdx.x;
    int tx = tid & 15, ty = tid >> 4;

    __shared__ float Qs[64][68];   // [d][qrow]
    __shared__ float Ks[64][68];   // [d][krow]
    __shared__ float Vs[64][68];   // [krow][d]
    __shared__ float Ps[64][68];   // [qrow][krow]

    size_t base = ((size_t)b * SEQ) * QKV_N + (size_t)h * HEAD_DIM;
    const float* q = qkv + base;
    const float* k = qkv + base + 1024;
    const float* v = qkv + base + 2048;
    size_t cbase = ((size_t)b * SEQ) * EMB + (size_t)h * HEAD_DIM;

#pragma unroll
    for (int t = 0; t < 4; ++t) {
        int f = tid + t * 256;
        int row = f >> 4, c4 = (f & 15) * 4;
        float4 qv = *(const float4*)(q + (size_t)(qt * 64 + row) * QKV_N + c4);
        Qs[c4 + 0][row] = qv.x;
        Qs[c4 + 1][row] = qv.y;
        Qs[c4 + 2][row] = qv.z;
        Qs[c4 + 3][row] = qv.w;
    }

    float m_i[4], l_i[4], o[4][4];
#pragma unroll
    for (int i = 0; i < 4; ++i) {
        m_i[i] = -1e30f;
        l_i[i] = 0.f;
#pragma unroll
        for (int j = 0; j < 4; ++j) o[i][j] = 0.f;
    }

    for (int kt = 0; kt <= qt; ++kt) {
        __syncthreads();
#pragma unroll
        for (int t = 0; t < 4; ++t) {
            int f = tid + t * 256;
            int row = f >> 4, c4 = (f & 15) * 4;
            float4 kv = *(const float4*)(k + (size_t)(kt * 64 + row) * QKV_N + c4);
            Ks[c4 + 0][row] = kv.x;
            Ks[c4 + 1][row] = kv.y;
            Ks[c4 + 2][row] = kv.z;
            Ks[c4 + 3][row] = kv.w;
            *(float4*)&Vs[row][c4] = *(const float4*)(v + (size_t)(kt * 64 + row) * QKV_N + c4);
        }
        __syncthreads();

        float s[4][4] = {};
#pragma unroll 16
        for (int d = 0; d < 64; ++d) {
            float4 a = *(const float4*)&Qs[d][ty * 4];
            float4 bb = *(const float4*)&Ks[d][tx * 4];
            float av[4] = {a.x, a.y, a.z, a.w};
            float bv[4] = {bb.x, bb.y, bb.z, bb.w};
#pragma unroll
            for (int i = 0; i < 4; ++i)
#pragma unroll
                for (int j = 0; j < 4; ++j)
                    s[i][j] = fmaf(av[i], bv[j], s[i][j]);
        }

        bool diag = (kt == qt);
#pragma unroll
        for (int i = 0; i < 4; ++i) {
            int ri = ty * 4 + i;
#pragma unroll
            for (int j = 0; j < 4; ++j) {
                float sv = s[i][j] * 0.125f;
                if (diag && (tx * 4 + j) > ri) sv = -1e30f;
                s[i][j] = sv;
            }
            float rm = fmaxf(fmaxf(s[i][0], s[i][1]), fmaxf(s[i][2], s[i][3]));
#pragma unroll
            for (int msk = 1; msk < 16; msk <<= 1)
                rm = fmaxf(rm, __shfl_xor(rm, msk));
            float m_new = fmaxf(m_i[i], rm);
            float p0 = __expf(s[i][0] - m_new);
            float p1 = __expf(s[i][1] - m_new);
            float p2 = __expf(s[i][2] - m_new);
            float p3 = __expf(s[i][3] - m_new);
            float rs = p0 + p1 + p2 + p3;
#pragma unroll
            for (int msk = 1; msk < 16; msk <<= 1)
                rs += __shfl_xor(rs, msk);
            float alpha = __expf(m_i[i] - m_new);
            l_i[i] = l_i[i] * alpha + rs;
            m_i[i] = m_new;
#pragma unroll
            for (int j = 0; j < 4; ++j) o[i][j] *= alpha;
            *(float4*)&Ps[ri][tx * 4] = make_float4(p0, p1, p2, p3);
        }
        __syncthreads();

#pragma unroll
        for (int c0 = 0; c0 < 16; ++c0) {
            float4 v0 = *(const float4*)&Vs[c0 * 4 + 0][tx * 4];
            float4 v1 = *(const float4*)&Vs[c0 * 4 + 1][tx * 4];
            float4 v2 = *(const float4*)&Vs[c0 * 4 + 2][tx * 4];
            float4 v3 = *(const float4*)&Vs[c0 * 4 + 3][tx * 4];
#pragma unroll
            for (int i = 0; i < 4; ++i) {
                float4 pr = *(const float4*)&Ps[ty * 4 + i][c0 * 4];
                o[i][0] = fmaf(pr.x, v0.x, o[i][0]);
                o[i][1] = fmaf(pr.x, v0.y, o[i][1]);
                o[i][2] = fmaf(pr.x, v0.z, o[i][2]);
                o[i][3] = fmaf(pr.x, v0.w, o[i][3]);
                o[i][0] = fmaf(pr.y, v1.x, o[i][0]);
                o[i][1] = fmaf(pr.y, v1.y, o[i][1]);
                o[i][2] = fmaf(pr.y, v1.z, o[i][2]);
                o[i][3] = fmaf(pr.y, v1.w, o[i][3]);
                o[i][0] = fmaf(pr.z, v2.x, o[i][0]);
                o[i][1] = fmaf(pr.z, v2.y, o[i][1]);
                o[i][2] = fmaf(pr.z, v2.z, o[i][2]);
                o[i][3] = fmaf(pr.z, v2.w, o[i][3]);
                o[i][0] = fmaf(pr.w, v3.x, o[i][0]);
                o[i][1] = fmaf(pr.w, v3.y, o[i][1]);
                o[i][2] = fmaf(pr.w, v3.z, o[i][2]);
                o[i][3] = fmaf(pr.w, v3.w, o[i][3]);
            }
        }
    }

#pragma unroll
    for (int i = 0; i < 4; ++i) {
        float inv = 1.0f / l_i[i];
        ushort4 ov;
        ov.x = f2bf(o[i][0] * inv);
        ov.y = f2bf(o[i][1] * inv);
        ov.z = f2bf(o[i][2] * inv);
        ov.w = f2bf(o[i][3] * inv);
        *(ushort4*)(ctx + cbase + (size_t)(qt * 64 + ty * 4 + i) * EMB + tx * 4) = ov;
    }
}

extern "C" void kernel_launch(void* const* d_in, const int* in_sizes, int n_in,
                              void* d_out, int out_size, void* d_ws, size_t ws_size,
                              hipStream_t stream) {
    const float* x    = (const float*)d_in[0];
    const float* Wq   = (const float*)d_in[1];
    const float* Wk   = (const float*)d_in[2];
    const float* Wv   = (const float*)d_in[3];
    const float* Wo   = (const float*)d_in[4];
    const float* bo   = (const float*)d_in[5];
    const float* W1   = (const float*)d_in[6];
    const float* b1   = (const float*)d_in[7];
    const float* W2   = (const float*)d_in[8];
    const float* b2   = (const float*)d_in[9];
    const float* ln1s = (const float*)d_in[10];
    const float* ln1b = (const float*)d_in[11];
    const float* ln2s = (const float*)d_in[12];
    const float* ln2b = (const float*)d_in[13];
    float* out = (float*)d_out;

    const size_t MiB = 1024 * 1024;
    uint8_t* w8 = (uint8_t*)d_ws;
    unsigned short* Wqkv_t = (unsigned short*)(w8);             //  6 MiB [3072][1024]
    unsigned short* Wo_t   = (unsigned short*)(w8 +  6 * MiB);  //  2 MiB [1024][1024]
    unsigned short* W1_t   = (unsigned short*)(w8 +  8 * MiB);  //  8 MiB [4096][1024]
    unsigned short* W2_t   = (unsigned short*)(w8 + 16 * MiB);  //  8 MiB [1024][4096]
    unsigned short* act_bf = (unsigned short*)(w8 + 24 * MiB);  //  8 MiB (h1/ctx/h2 share)
    float*          qkv    = (float*)(w8 + 32 * MiB);           // 48 MiB [4096][3072]
    unsigned short* u_bf   = (unsigned short*)(w8 + 32 * MiB);  // 32 MiB (aliases qkv, dead)
    float*          x1     = (float*)(w8 + 80 * MiB);           // 16 MiB

    // 0) weight convert+transpose (bf16, [N][K])
    tconv_kernel<<<dim3(16, 16), 256, 0, stream>>>(Wq, Wqkv_t, EMB, EMB);
    tconv_kernel<<<dim3(16, 16), 256, 0, stream>>>(Wk, Wqkv_t + (size_t)1024 * EMB, EMB, EMB);
    tconv_kernel<<<dim3(16, 16), 256, 0, stream>>>(Wv, Wqkv_t + (size_t)2048 * EMB, EMB, EMB);
    tconv_kernel<<<dim3(16, 16), 256, 0, stream>>>(Wo, Wo_t, EMB, EMB);
    tconv_kernel<<<dim3(64, 16), 256, 0, stream>>>(W1, W1_t, EMB, FF_DIM);
    tconv_kernel<<<dim3(16, 64), 256, 0, stream>>>(W2, W2_t, FF_DIM, EMB);

    // 1) LN1 -> bf16
    ln_bf16_kernel<<<NTOK, 256, 0, stream>>>(x, ln1s, ln1b, act_bf);

    // 2) fused QKV: qkv = h @ Wqkv  [4096,3072]
    gemm_bf16_kernel<<<dim3(QKV_N / 128, NTOK / 128), 256, 0, stream>>>(
        act_bf, Wqkv_t, qkv, nullptr, NTOK, QKV_N, EMB, nullptr, nullptr, 0);

    // 3) causal attention -> ctx bf16
    flash_attn_kernel<<<dim3(SEQ / 64, HEADS, BATCH), 256, 0, stream>>>(qkv, act_bf);

    // 4) x1 = x + ctx @ Wo + bo
    gemm_bf16_kernel<<<dim3(EMB / 128, NTOK / 128), 256, 0, stream>>>(
        act_bf, Wo_t, x1, nullptr, NTOK, EMB, EMB, bo, x, 0);

    // 5) LN2 -> bf16
    ln_bf16_kernel<<<NTOK, 256, 0, stream>>>(x1, ln2s, ln2b, act_bf);

    // 6) u = gelu(h2 @ W1 + b1) -> bf16  [4096,4096]
    gemm_bf16_kernel<<<dim3(FF_DIM / 128, NTOK / 128), 256, 0, stream>>>(
        act_bf, W1_t, nullptr, u_bf, NTOK, FF_DIM, EMB, b1, nullptr, 1);

    // 7) out = x1 + u @ W2 + b2
    gemm_bf16_kernel<<<dim3(EMB / 128, NTOK / 128), 256, 0, stream>>>(
        u_bf, W2_t, out, nullptr, NTOK, EMB, FF_DIM, b2, x1, 0);
}

// Round 4
// 625.149 us; speedup vs baseline: 11.2314x; 2.0603x over previous
//
#include <hip/hip_runtime.h>
#include <hip/hip_bf16.h>
#include <math.h>

#define EMB 1024
#define HEADS 16
#define HEAD_DIM 64
#define FF_DIM 4096
#define SEQ 2048
#define BATCH 2
#define NTOK (BATCH * SEQ)   // 4096 rows
#define LN_EPS 1e-5f
#define QKV_N 3072

typedef __attribute__((ext_vector_type(8))) short s8v;   // 8 bf16 (4 VGPRs)
typedef __attribute__((ext_vector_type(4))) float f4v;   // MFMA accumulator

__device__ __forceinline__ unsigned short f2bf(float f) {
    union { __hip_bfloat16 h; unsigned short u; } cv;
    cv.h = __float2bfloat16(f);
    return cv.u;
}

__device__ __forceinline__ float gelu_f(float x) {
    const float c = 0.7978845608028654f;  // sqrt(2/pi)
    float x3 = x * x * x;
    return 0.5f * x * (1.0f + tanhf(c * (x + 0.044715f * x3)));
}

#define GLDS(gp, lp)                                                        \
    __builtin_amdgcn_global_load_lds(                                       \
        (const __attribute__((address_space(1))) void*)(gp),                \
        (__attribute__((address_space(3))) void*)(lp), 16, 0, 0)

// ---------------- LayerNorm -> bf16 out ----------------------------------------------
__global__ __launch_bounds__(256) void ln_bf16_kernel(const float* __restrict__ x,
                                                      const float* __restrict__ scale,
                                                      const float* __restrict__ shift,
                                                      unsigned short* __restrict__ out) {
    int row = blockIdx.x;
    int tid = threadIdx.x;
    const float4 xv = ((const float4*)(x + (size_t)row * EMB))[tid];
    float s  = xv.x + xv.y + xv.z + xv.w;
    float ss = xv.x * xv.x + xv.y * xv.y + xv.z * xv.z + xv.w * xv.w;
    __shared__ float2 red[256];
    red[tid] = make_float2(s, ss);
    __syncthreads();
    for (int off = 128; off > 0; off >>= 1) {
        if (tid < off) {
            red[tid].x += red[tid + off].x;
            red[tid].y += red[tid + off].y;
        }
        __syncthreads();
    }
    float mean = red[0].x * (1.0f / EMB);
    float var  = red[0].y * (1.0f / EMB) - mean * mean;
    float rstd = rsqrtf(var + LN_EPS);
    float4 sc4 = ((const float4*)scale)[tid];
    float4 sh4 = ((const float4*)shift)[tid];
    ushort4 o;
    o.x = f2bf(sc4.x * (xv.x - mean) * rstd + sh4.x);
    o.y = f2bf(sc4.y * (xv.y - mean) * rstd + sh4.y);
    o.z = f2bf(sc4.z * (xv.z - mean) * rstd + sh4.z);
    o.w = f2bf(sc4.w * (xv.w - mean) * rstd + sh4.w);
    *(ushort4*)(out + (size_t)row * EMB + tid * 4) = o;
}

// ---------------- fp32 [K][N] -> bf16 [N][K] transpose-convert ------------------------
__global__ __launch_bounds__(256) void tconv_kernel(const float* __restrict__ W,
                                                    unsigned short* __restrict__ Wt,
                                                    int K, int N) {
    __shared__ float t[64][65];
    int n0 = blockIdx.x * 64, k0 = blockIdx.y * 64;
    int tid = threadIdx.x;
#pragma unroll
    for (int it = 0; it < 4; ++it) {
        int f = tid + it * 256;
        int r = f >> 4, c = (f & 15) * 4;
        float4 w = *(const float4*)(W + (size_t)(k0 + r) * N + n0 + c);
        t[r][c] = w.x; t[r][c + 1] = w.y; t[r][c + 2] = w.z; t[r][c + 3] = w.w;
    }
    __syncthreads();
#pragma unroll
    for (int it = 0; it < 4; ++it) {
        int f = tid + it * 256;
        int rn = f >> 4, ck = (f & 15) * 4;
        ushort4 o;
        o.x = f2bf(t[ck + 0][rn]);
        o.y = f2bf(t[ck + 1][rn]);
        o.z = f2bf(t[ck + 2][rn]);
        o.w = f2bf(t[ck + 3][rn]);
        *(ushort4*)(Wt + (size_t)(n0 + rn) * K + k0 + ck) = o;
    }
}

// ---------------- bf16 MFMA GEMM: C[M,N] = A[M,K] @ Bt[N,K]^T -------------------------
// 128x128 tile, BK=32, 256 threads = 4 waves in 2x2, each wave 4x4 of 16x16x32 MFMA.
// qkv_mode=1: N==3072, write q/k bf16 to Cb [M][2048], v transposed to vt [B*H*64][SEQ].
__global__ __launch_bounds__(256) void gemm_bf16_kernel(
    const unsigned short* __restrict__ A,   // [M,K] bf16
    const unsigned short* __restrict__ Bt,  // [N,K] bf16
    float* __restrict__ Cf,                 // fp32 out (or null)
    unsigned short* __restrict__ Cb,        // bf16 out (or null)
    int M, int N, int K,
    const float* __restrict__ bias,
    const float* __restrict__ residual,
    int do_gelu, int qkv_mode,
    unsigned short* __restrict__ vt)
{
    __shared__ short As[4096];   // 4 planes x 128 rows x 8 bf16 = 8 KiB
    __shared__ short Bs[4096];

    int tid = threadIdx.x;
    int m0 = blockIdx.y * 128;
    int n0 = blockIdx.x * 128;
    int wv = tid >> 6, lane = tid & 63;
    int wr = wv >> 1, wc = wv & 1;

    f4v acc[4][4];
#pragma unroll
    for (int i = 0; i < 4; ++i)
#pragma unroll
        for (int j = 0; j < 4; ++j) {
            f4v z = {0.f, 0.f, 0.f, 0.f};
            acc[i][j] = z;
        }

    int ra = tid & 127, ka = tid >> 7;
    const char* Ag0 = (const char*)A + (size_t)(m0 + ra) * (K << 1) + ka * 16;
    const char* Bg0 = (const char*)Bt + (size_t)(n0 + ra) * (K << 1) + ka * 16;
    short* Al0 = As + tid * 8;
    short* Al1 = As + (tid + 256) * 8;
    short* Bl0 = Bs + tid * 8;
    short* Bl1 = Bs + (tid + 256) * 8;

    int kgrp = lane >> 4;
    const short* Af = As + ((size_t)kgrp * 128 + wr * 64 + (lane & 15)) * 8;
    const short* Bf = Bs + ((size_t)kgrp * 128 + wc * 64 + (lane & 15)) * 8;

    int Kb = K << 1;
    for (int kb = 0; kb < Kb; kb += 64) {
        __syncthreads();
        GLDS(Ag0 + kb, Al0);
        GLDS(Ag0 + kb + 32, Al1);
        GLDS(Bg0 + kb, Bl0);
        GLDS(Bg0 + kb + 32, Bl1);
        __syncthreads();

        s8v af[4], bf[4];
#pragma unroll
        for (int i = 0; i < 4; ++i) af[i] = *(const s8v*)(Af + i * 128);
#pragma unroll
        for (int j = 0; j < 4; ++j) bf[j] = *(const s8v*)(Bf + j * 128);
#pragma unroll
        for (int i = 0; i < 4; ++i)
#pragma unroll
            for (int j = 0; j < 4; ++j)
                acc[i][j] = __builtin_amdgcn_mfma_f32_16x16x32_bf16(af[i], bf[j], acc[i][j], 0, 0, 0);
    }

    // epilogue: C/D layout col=lane&15, row=(lane>>4)*4+reg
    int cn  = n0 + wc * 64 + (lane & 15);
    int cm0 = m0 + wr * 64 + (lane >> 4) * 4;

    if (qkv_mode) {
        if (n0 < 2048) {
            // q/k part: row-major bf16 [M][2048]
#pragma unroll
            for (int j = 0; j < 4; ++j) {
                int gn = cn + j * 16;
#pragma unroll
                for (int i = 0; i < 4; ++i)
#pragma unroll
                    for (int r = 0; r < 4; ++r)
                        Cb[(size_t)(cm0 + i * 16 + r) * 2048 + gn] = f2bf(acc[i][j][r]);
            }
        } else {
            // v part: vt[(b*16+h)*64+d][s] bf16, packed 4 consecutive s
#pragma unroll
            for (int j = 0; j < 4; ++j) {
                int gn = cn + j * 16 - 2048;       // 0..1023
                size_t drow = (size_t)gn * SEQ;    // ((b?)*16+h)*64+d collapses: gn = h*64+d
#pragma unroll
                for (int i = 0; i < 4; ++i) {
                    int gm0 = cm0 + i * 16;
                    int bb = gm0 >> 11, s0 = gm0 & 2047;
                    ushort4 pk;
                    pk.x = f2bf(acc[i][j][0]);
                    pk.y = f2bf(acc[i][j][1]);
                    pk.z = f2bf(acc[i][j][2]);
                    pk.w = f2bf(acc[i][j][3]);
                    *(ushort4*)(vt + ((size_t)bb * 1024 + gn) * SEQ + s0) = pk;
                    (void)drow;
                }
            }
        }
        return;
    }

#pragma unroll
    for (int j = 0; j < 4; ++j) {
        int gn = cn + j * 16;
        float bj = bias ? bias[gn] : 0.f;
#pragma unroll
        for (int i = 0; i < 4; ++i) {
#pragma unroll
            for (int r = 0; r < 4; ++r) {
                int gm = cm0 + i * 16 + r;
                float vv = acc[i][j][r] + bj;
                if (do_gelu) vv = gelu_f(vv);
                if (residual) vv += residual[(size_t)gm * N + gn];
                if (Cf) Cf[(size_t)gm * N + gn] = vv;
                else    Cb[(size_t)gm * N + gn] = f2bf(vv);
            }
        }
    }
}

// ---------------- MFMA flash attention ------------------------------------------------
// Block = (qt 128-row tile, head, batch); 4 waves x 32 q-rows. K-tiles of 64 keys.
// qk: bf16 [NTOK][2048] (q | k per head); vt: bf16 [B*H*64][SEQ]; ctx: bf16 [NTOK][EMB].
__global__ __launch_bounds__(256) void flash_attn_mfma_kernel(
    const unsigned short* __restrict__ qk,
    const unsigned short* __restrict__ vt,
    unsigned short* __restrict__ ctx)
{
    int qt = blockIdx.x;   // 0..15
    int h  = blockIdx.y;   // 0..15
    int b  = blockIdx.z;   // 0..1
    int tid = threadIdx.x;
    int w = tid >> 6, lane = tid & 63;
    int quad = lane >> 4, ln = lane & 15;

    __shared__ short Qs[8192];   // [kc:8][row:128][8]  16 KB
    __shared__ short Ks[4096];   // [kc:8][key:64][8]    8 KB
    __shared__ short Vts[4096];  // [kc(key):8][d:64][8] 8 KB
    __shared__ short Ps[8192];   // [kc(key):8][row:128][8] 16 KB (wave-private rows)

    size_t qrow0 = (size_t)b * SEQ + (size_t)qt * 128;

    // stage Q tile (128 rows x 64 d): 1024 chunks of 16 B
#pragma unroll
    for (int i = 0; i < 4; ++i) {
        int c = tid + i * 256;
        int row = c & 127, kc = c >> 7;
        GLDS((const char*)(qk + (qrow0 + row) * 2048 + h * 64 + kc * 8),
             (char*)Qs + (size_t)c * 16);
    }

    float m_i[2][4], l_i[2][4];
    f4v o[2][4];
#pragma unroll
    for (int mb = 0; mb < 2; ++mb)
#pragma unroll
        for (int r = 0; r < 4; ++r) {
            m_i[mb][r] = -1e30f;
            l_i[mb][r] = 0.f;
        }
#pragma unroll
    for (int mb = 0; mb < 2; ++mb)
#pragma unroll
        for (int db = 0; db < 4; ++db) {
            f4v z = {0.f, 0.f, 0.f, 0.f};
            o[mb][db] = z;
        }

    int kts = 2 * qt + 2;
    size_t kbase = (size_t)b * SEQ * 2048 + 1024 + h * 64;
    size_t vbase = ((size_t)b * 1024 + h * 64) * SEQ;

    for (int kt = 0; kt < kts; ++kt) {
        __syncthreads();   // all waves done reading Ks/Vts of prev iter
#pragma unroll
        for (int i = 0; i < 2; ++i) {
            int c = tid + i * 256;
            int rr = c & 63, kc = c >> 6;
            GLDS((const char*)(qk + kbase + (size_t)(kt * 64 + rr) * 2048 + kc * 8),
                 (char*)Ks + (size_t)c * 16);
            GLDS((const char*)(vt + vbase + (size_t)rr * SEQ + kt * 64 + kc * 8),
                 (char*)Vts + (size_t)c * 16);
        }
        __syncthreads();   // drain staging

        // wave active if its rows can see any key of this tile
        if (kt * 64 <= qt * 128 + w * 32 + 31) {
            // ---- S = Q K^T ----
            f4v s[2][4];
#pragma unroll
            for (int mb = 0; mb < 2; ++mb)
#pragma unroll
                for (int nb = 0; nb < 4; ++nb) {
                    f4v z = {0.f, 0.f, 0.f, 0.f};
                    s[mb][nb] = z;
                }
#pragma unroll
            for (int ks = 0; ks < 2; ++ks) {
                s8v af[2];
#pragma unroll
                for (int mb = 0; mb < 2; ++mb)
                    af[mb] = *(const s8v*)(Qs + ((size_t)(ks * 4 + quad) * 128 + w * 32 + mb * 16 + ln) * 8);
#pragma unroll
                for (int nb = 0; nb < 4; ++nb) {
                    s8v bfr = *(const s8v*)(Ks + ((size_t)(ks * 4 + quad) * 64 + nb * 16 + ln) * 8);
#pragma unroll
                    for (int mb = 0; mb < 2; ++mb)
                        s[mb][nb] = __builtin_amdgcn_mfma_f32_16x16x32_bf16(af[mb], bfr, s[mb][nb], 0, 0, 0);
                }
            }

            // ---- online softmax (rows wave-private) ----
            bool diag = (kt >= 2 * qt);
#pragma unroll
            for (int mb = 0; mb < 2; ++mb) {
#pragma unroll
                for (int r = 0; r < 4; ++r) {
                    int rloc = w * 32 + mb * 16 + quad * 4 + r;
                    float sv[4];
#pragma unroll
                    for (int nb = 0; nb < 4; ++nb) {
                        float x = s[mb][nb][r] * 0.125f;
                        if (diag && (kt * 64 + nb * 16 + ln > qt * 128 + rloc)) x = -1e30f;
                        sv[nb] = x;
                    }
                    float rm = fmaxf(fmaxf(sv[0], sv[1]), fmaxf(sv[2], sv[3]));
#pragma unroll
                    for (int msk = 1; msk < 16; msk <<= 1)
                        rm = fmaxf(rm, __shfl_xor(rm, msk));
                    float mo = m_i[mb][r];
                    float mn = fmaxf(mo, rm);
                    float al = __expf(mo - mn);
                    float p[4];
                    float rs = 0.f;
#pragma unroll
                    for (int nb = 0; nb < 4; ++nb) {
                        p[nb] = __expf(sv[nb] - mn);
                        rs += p[nb];
                    }
#pragma unroll
                    for (int msk = 1; msk < 16; msk <<= 1)
                        rs += __shfl_xor(rs, msk);
                    m_i[mb][r] = mn;
                    l_i[mb][r] = l_i[mb][r] * al + rs;
#pragma unroll
                    for (int db = 0; db < 4; ++db) o[mb][db][r] *= al;
#pragma unroll
                    for (int nb = 0; nb < 4; ++nb) {
                        int col = nb * 16 + ln;
                        Ps[(size_t)(col >> 3) * 1024 + (size_t)rloc * 8 + (col & 7)] = f2bf(p[nb]);
                    }
                }
            }

            // ---- O += P V ---- (reads own wave's Ps rows: no barrier needed)
#pragma unroll
            for (int ks = 0; ks < 2; ++ks) {
                s8v pf[2];
#pragma unroll
                for (int mb = 0; mb < 2; ++mb)
                    pf[mb] = *(const s8v*)(Ps + ((size_t)(ks * 4 + quad) * 128 + w * 32 + mb * 16 + ln) * 8);
#pragma unroll
                for (int db = 0; db < 4; ++db) {
                    s8v vf = *(const s8v*)(Vts + ((size_t)(ks * 4 + quad) * 64 + db * 16 + ln) * 8);
#pragma unroll
                    for (int mb = 0; mb < 2; ++mb)
                        o[mb][db] = __builtin_amdgcn_mfma_f32_16x16x32_bf16(pf[mb], vf, o[mb][db], 0, 0, 0);
                }
            }
        }
    }

    // epilogue: normalize + write ctx
#pragma unroll
    for (int mb = 0; mb < 2; ++mb)
#pragma unroll
        for (int r = 0; r < 4; ++r) {
            float inv = 1.0f / l_i[mb][r];
            size_t row = qrow0 + w * 32 + mb * 16 + quad * 4 + r;
#pragma unroll
            for (int db = 0; db < 4; ++db)
                ctx[row * EMB + h * 64 + db * 16 + ln] = f2bf(o[mb][db][r] * inv);
        }
}

extern "C" void kernel_launch(void* const* d_in, const int* in_sizes, int n_in,
                              void* d_out, int out_size, void* d_ws, size_t ws_size,
                              hipStream_t stream) {
    const float* x    = (const float*)d_in[0];
    const float* Wq   = (const float*)d_in[1];
    const float* Wk   = (const float*)d_in[2];
    const float* Wv   = (const float*)d_in[3];
    const float* Wo   = (const float*)d_in[4];
    const float* bo   = (const float*)d_in[5];
    const float* W1   = (const float*)d_in[6];
    const float* b1   = (const float*)d_in[7];
    const float* W2   = (const float*)d_in[8];
    const float* b2   = (const float*)d_in[9];
    const float* ln1s = (const float*)d_in[10];
    const float* ln1b = (const float*)d_in[11];
    const float* ln2s = (const float*)d_in[12];
    const float* ln2b = (const float*)d_in[13];
    float* out = (float*)d_out;

    const size_t MiB = 1024 * 1024;
    uint8_t* w8 = (uint8_t*)d_ws;
    unsigned short* Wqkv_t = (unsigned short*)(w8);             //  6 MiB [3072][1024]
    unsigned short* Wo_t   = (unsigned short*)(w8 +  6 * MiB);  //  2 MiB [1024][1024]
    unsigned short* W1_t   = (unsigned short*)(w8 +  8 * MiB);  //  8 MiB [4096][1024]
    unsigned short* W2_t   = (unsigned short*)(w8 + 16 * MiB);  //  8 MiB [1024][4096]
    unsigned short* act_bf = (unsigned short*)(w8 + 24 * MiB);  //  8 MiB (h1/ctx/h2)
    unsigned short* qk_bf  = (unsigned short*)(w8 + 32 * MiB);  // 16 MiB [4096][2048]
    unsigned short* vt     = (unsigned short*)(w8 + 48 * MiB);  //  8 MiB [2*16*64][2048]
    unsigned short* u_bf   = (unsigned short*)(w8 + 32 * MiB);  // 32 MiB (reuses qk+vt, dead)
    float*          x1     = (float*)(w8 + 64 * MiB);           // 16 MiB

    // 0) weight convert+transpose (bf16, [N][K])
    tconv_kernel<<<dim3(16, 16), 256, 0, stream>>>(Wq, Wqkv_t, EMB, EMB);
    tconv_kernel<<<dim3(16, 16), 256, 0, stream>>>(Wk, Wqkv_t + (size_t)1024 * EMB, EMB, EMB);
    tconv_kernel<<<dim3(16, 16), 256, 0, stream>>>(Wv, Wqkv_t + (size_t)2048 * EMB, EMB, EMB);
    tconv_kernel<<<dim3(16, 16), 256, 0, stream>>>(Wo, Wo_t, EMB, EMB);
    tconv_kernel<<<dim3(64, 16), 256, 0, stream>>>(W1, W1_t, EMB, FF_DIM);
    tconv_kernel<<<dim3(16, 64), 256, 0, stream>>>(W2, W2_t, FF_DIM, EMB);

    // 1) LN1 -> bf16
    ln_bf16_kernel<<<NTOK, 256, 0, stream>>>(x, ln1s, ln1b, act_bf);

    // 2) fused QKV (q/k row-major bf16, v transposed to vt)
    gemm_bf16_kernel<<<dim3(QKV_N / 128, NTOK / 128), 256, 0, stream>>>(
        act_bf, Wqkv_t, nullptr, qk_bf, NTOK, QKV_N, EMB, nullptr, nullptr, 0, 1, vt);

    // 3) MFMA flash attention -> ctx bf16
    flash_attn_mfma_kernel<<<dim3(SEQ / 128, HEADS, BATCH), 256, 0, stream>>>(qk_bf, vt, act_bf);

    // 4) x1 = x + ctx @ Wo + bo
    gemm_bf16_kernel<<<dim3(EMB / 128, NTOK / 128), 256, 0, stream>>>(
        act_bf, Wo_t, x1, nullptr, NTOK, EMB, EMB, bo, x, 0, 0, nullptr);

    // 5) LN2 -> bf16
    ln_bf16_kernel<<<NTOK, 256, 0, stream>>>(x1, ln2s, ln2b, act_bf);

    // 6) u = gelu(h2 @ W1 + b1) -> bf16
    gemm_bf16_kernel<<<dim3(FF_DIM / 128, NTOK / 128), 256, 0, stream>>>(
        act_bf, W1_t, nullptr, u_bf, NTOK, FF_DIM, EMB, b1, nullptr, 1, 0, nullptr);

    // 7) out = x1 + u @ W2 + b2
    gemm_bf16_kernel<<<dim3(EMB / 128, NTOK / 128), 256, 0, stream>>>(
        u_bf, W2_t, out, nullptr, NTOK, EMB, FF_DIM, b2, x1, 0, 0, nullptr);
}